// Round 4
// baseline (495.093 us; speedup 1.0000x reference)
//
#include <hip/hip_runtime.h>
#include <hip/hip_cooperative_groups.h>
#include <math.h>

namespace cg = cooperative_groups;

#define B_N     16384
#define D_N     512
#define NPAIR   8192
#define NBUCKET 4096
#define GRID_N  256              // 1 block per CU -> co-residency guaranteed
#define BLOCK_N 1024             // 16 waves

__device__ __forceinline__ float wave_reduce(float v) {
    #pragma unroll
    for (int m = 32; m >= 1; m >>= 1) v += __shfl_xor(v, m, 64);
    return v;
}

__device__ __forceinline__ float dot4(float4 a, float4 b) {
    return a.x*b.x + a.y*b.y + a.z*b.z + a.w*b.w;
}

__device__ __forceinline__ int bucket_of(float t) {
    return min(max((int)(t * 4096.0f), 0), NBUCKET - 1);   // exact pow2 scale, monotone
}

__device__ __forceinline__ unsigned long long key_of(float t, int i) {
    // stable argsort(-t): j at-or-before i (j!=i)  <=>  key_j > key_i
    return (((unsigned long long)__float_as_uint(t)) << 14) |
           (unsigned long long)(B_N - 1 - i);
}

// ---------------------------------------------------------------------------
// One cooperative kernel: 256 blocks x 1024 threads.
// Wave 0 of block b owns Cox elements [b*64, b*64+64); all waves do con pairs.
// ---------------------------------------------------------------------------
__global__ __launch_bounds__(BLOCK_N) void k_all(
        const float* __restrict__ rep1,
        const float* __restrict__ rep2,
        const float* __restrict__ rep3,
        const float* __restrict__ hazard,
        const float* __restrict__ score,
        const float* __restrict__ time,
        const int*   __restrict__ event,
        const int*   __restrict__ x1_idx,
        const int*   __restrict__ x2_idx,
        float* __restrict__ partCon,             // [256]
        float* __restrict__ scal,                // [0]=cox [1]=nll [2]=ev
        int*   __restrict__ counts,              // [NBUCKET]
        float* __restrict__ sumE,                // [NBUCKET]
        int*   __restrict__ pos,                 // [NBUCKET] -> end offsets after scatter
        float* __restrict__ cumH,                // [NBUCKET]
        unsigned long long* __restrict__ skey,   // [B_N]
        float* __restrict__ sev,                 // [B_N]
        float* __restrict__ out)
{
    __shared__ int   shI[NBUCKET];     // 16 KB (scan staging, block 0)
    __shared__ float shF[NBUCKET];     // 16 KB
    __shared__ int   sci[BLOCK_N];     // 4 KB
    __shared__ float scf[BLOCK_N];     // 4 KB
    __shared__ float wsum[16];

    cg::grid_group grid = cg::this_grid();
    const int tid  = threadIdx.x;
    const int lane = tid & 63;
    const int wave = tid >> 6;
    const int blk  = blockIdx.x;

    // ---- phase 0: zero counts+sumE (contiguous 8192 words) + scal ----
    if (tid < 32) {
        ((int*)counts)[blk * 32 + tid] = 0;      // counts[0..4095] then sumE[0..4095]
    }
    if (blk == 0 && tid >= 32 && tid < 40) scal[tid - 32] = 0.f;
    grid.sync();

    // ---- phase 1: cox histogram + NLL (wave 0) and con pairs (all waves) ----
    float t_i = 0.f, h_i = 0.f, e_i = 0.f;
    int   b_i = 0, ev_i = 0;
    unsigned long long k_i = 0;
    if (wave == 0) {
        const int i = blk * 64 + lane;
        t_i  = time[i];
        h_i  = hazard[i];
        ev_i = event[i];
        e_i  = __expf(h_i);
        b_i  = bucket_of(t_i);
        k_i  = key_of(t_i, i);
        atomicAdd(&counts[b_i], 1);
        atomicAdd(&sumE[b_i], e_i);
        float nll_p = score[i * 2 + ev_i];
        float ev_p  = (float)ev_i;
        nll_p = wave_reduce(nll_p);
        ev_p  = wave_reduce(ev_p);
        if (lane == 0) { atomicAdd(&scal[1], nll_p); atomicAdd(&scal[2], ev_p); }
    }

    float conp = 0.f;
    #pragma unroll
    for (int r = 0; r < 2; ++r) {
        const int p  = (blk * 16 + wave) * 2 + r;
        const int ia = x1_idx[p];
        const int ib = x2_idx[p];
        const float4* A1 = (const float4*)(rep1 + (size_t)ia * D_N);
        const float4* A2 = (const float4*)(rep2 + (size_t)ia * D_N);
        const float4* A3 = (const float4*)(rep3 + (size_t)ia * D_N);
        const float4* B1 = (const float4*)(rep1 + (size_t)ib * D_N);
        const float4* B2 = (const float4*)(rep2 + (size_t)ib * D_N);
        const float4* B3 = (const float4*)(rep3 + (size_t)ib * D_N);

        float v[15];
        #pragma unroll
        for (int k = 0; k < 15; ++k) v[k] = 0.f;
        #pragma unroll
        for (int rr = 0; rr < 2; ++rr) {
            const int k = lane + rr * 64;        // 128 float4 per row
            float4 a1 = A1[k], a2 = A2[k], a3 = A3[k];
            float4 b1 = B1[k], b2 = B2[k], b3 = B3[k];
            v[0]  += dot4(a1, a1); v[1]  += dot4(a2, a2); v[2]  += dot4(a3, a3);
            v[3]  += dot4(b1, b1); v[4]  += dot4(b2, b2); v[5]  += dot4(b3, b3);
            v[6]  += dot4(a1, a2); v[7]  += dot4(a1, a3); v[8]  += dot4(a2, a3);
            v[9]  += dot4(b1, b2); v[10] += dot4(b1, b3); v[11] += dot4(b2, b3);
            v[12] += dot4(a1, b1); v[13] += dot4(a2, b2); v[14] += dot4(a3, b3);
        }
        #pragma unroll
        for (int k = 0; k < 15; ++k) v[k] = wave_reduce(v[k]);

        float n1a = fmaxf(sqrtf(v[0]), 1e-8f), n2a = fmaxf(sqrtf(v[1]), 1e-8f), n3a = fmaxf(sqrtf(v[2]), 1e-8f);
        float n1b = fmaxf(sqrtf(v[3]), 1e-8f), n2b = fmaxf(sqrtf(v[4]), 1e-8f), n3b = fmaxf(sqrtf(v[5]), 1e-8f);
        float dxx = v[6]/(n1a*n2a) + v[7]/(n1a*n3a) + v[8]/(n2a*n3a);
        float dyy = v[9]/(n1b*n2b) + v[10]/(n1b*n3b) + v[11]/(n2b*n3b);
        float dxy = v[12]/(n1a*n1b) + v[13]/(n2a*n2b) + v[14]/(n3a*n3b);
        float s = 0.2f + dxy - 0.5f*dxx - 0.5f*dyy;
        conp += log1pf(expf(s));                 // same value in all 64 lanes
    }
    if (lane == 0) wsum[wave] = conp;
    __syncthreads();
    if (tid == 0) {
        float t = 0.f;
        #pragma unroll
        for (int w = 0; w < 16; ++w) t += wsum[w];
        partCon[blk] = t;
    }
    __threadfence();
    grid.sync();

    // ---- phase 2: block 0 scans buckets -> pos (excl prefix), cumH (strict-greater suffix) ----
    if (blk == 0) {
        int   c[4]; float f[4];
        #pragma unroll
        for (int k = 0; k < 4; ++k) {
            c[k] = counts[tid * 4 + k];
            f[k] = sumE[tid * 4 + k];
        }
        int cex[4]; int s = 0; float fs = 0.f;
        #pragma unroll
        for (int k = 0; k < 4; ++k) { cex[k] = s; s += c[k]; fs += f[k]; }
        sci[tid] = s;
        scf[tid] = fs;
        __syncthreads();
        for (int d = 1; d < BLOCK_N; d <<= 1) {
            int   vi = (tid >= d) ? sci[tid - d] : 0;
            float vf = (tid >= d) ? scf[tid - d] : 0.f;
            __syncthreads();
            sci[tid] += vi;
            scf[tid] += vf;
            __syncthreads();
        }
        const int   ebase = sci[tid] - s;
        const float ftot  = scf[BLOCK_N - 1];
        float run = ftot - scf[tid];
        #pragma unroll
        for (int k = 0; k < 4; ++k) shI[tid * 4 + k] = ebase + cex[k];
        #pragma unroll
        for (int k = 3; k >= 0; --k) { shF[tid * 4 + k] = run; run += f[k]; }
        #pragma unroll
        for (int k = 0; k < 4; ++k) {
            pos[tid * 4 + k]  = shI[tid * 4 + k];
            cumH[tid * 4 + k] = shF[tid * 4 + k];
        }
        __threadfence();
    }
    grid.sync();

    // ---- phase 3: parallel counting scatter (wave 0 of every block) ----
    if (wave == 0) {
        const int p = atomicAdd(&pos[b_i], 1);   // pos becomes bucket end offsets
        skey[p] = k_i;
        sev[p]  = e_i;
    }
    __threadfence();
    grid.sync();

    // ---- phase 4: in-bucket correction + cox partial (wave 0 of every block) ----
    if (wave == 0) {
        const int lo = (b_i == 0) ? 0 : pos[b_i - 1];
        const int hi = pos[b_i];
        float cum = cumH[b_i] + e_i;             // strictly-greater buckets + self
        for (int q = lo; q < hi; ++q) {
            if (skey[q] > k_i) cum += sev[q];
        }
        float cox_p = ev_i ? (h_i - logf(cum + 1e-6f)) : 0.f;
        cox_p = wave_reduce(cox_p);
        if (lane == 0) atomicAdd(&scal[0], cox_p);
    }
    __threadfence();
    grid.sync();

    // ---- phase 5: block 0 combines everything -> out[0] ----
    if (blk == 0) {
        float con = (tid < GRID_N) ? partCon[tid] : 0.f;
        con = wave_reduce(con);
        if (lane == 0) scf[wave] = con;
        __syncthreads();
        if (tid == 0) {
            float C = 0.f;
            #pragma unroll
            for (int w = 0; w < 16; ++w) C += scf[w];
            const float X = scal[0], N = scal[1], E = scal[2];
            const float nll_t = -N / (float)B_N;
            const float cox_t = -X / (E + 1e-6f);
            const float con_t = C / (float)NPAIR;
            out[0] = nll_t + cox_t + 0.3f * con_t;
        }
    }
}

extern "C" void kernel_launch(void* const* d_in, const int* in_sizes, int n_in,
                              void* d_out, int out_size, void* d_ws, size_t ws_size,
                              hipStream_t stream)
{
    const float* rep1   = (const float*)d_in[0];
    const float* rep2   = (const float*)d_in[1];
    const float* rep3   = (const float*)d_in[2];
    const float* hazard = (const float*)d_in[3];
    const float* score  = (const float*)d_in[4];
    const float* time_  = (const float*)d_in[5];
    const int*   event  = (const int*)d_in[6];
    const int*   x1     = (const int*)d_in[7];
    const int*   x2     = (const int*)d_in[8];
    float* out = (float*)d_out;

    char* w = (char*)d_ws;
    float* partCon = (float*)(w + 0);                    // 1 KB
    float* scal    = (float*)(w + 1024);                 // 32 B
    int*   counts  = (int*)  (w + 4096);                 // 16 KB  | contiguous with
    float* sumE    = (float*)(w + 4096 + 16384);         // 16 KB  | counts for zeroing
    int*   pos     = (int*)  (w + 4096 + 32768);         // 16 KB
    float* cumH    = (float*)(w + 4096 + 49152);         // 16 KB
    unsigned long long* skey = (unsigned long long*)(w + 4096 + 65536);   // 128 KB
    float* sev     = (float*)(w + 4096 + 65536 + 131072);                 // 64 KB

    void* args[] = { &rep1, &rep2, &rep3, &hazard, &score, &time_, &event,
                     &x1, &x2, &partCon, &scal, &counts, &sumE, &pos, &cumH,
                     &skey, &sev, &out };
    hipLaunchCooperativeKernel((const void*)k_all, dim3(GRID_N), dim3(BLOCK_N),
                               args, 0, stream);
}

// Round 5
// 388.561 us; speedup vs baseline: 1.2742x; 1.2742x over previous
//
#include <hip/hip_runtime.h>
#include <math.h>

#define B_N     16384
#define D_N     512
#define NPAIR   8192
#define NBUCKET 16384            // avg 1 element/bucket
#define CON_BLOCKS 2048
#define COX_BLOCKS 64
#define TOT_BLOCKS (CON_BLOCKS + COX_BLOCKS)
#define PREP_BLOCKS 16

__device__ __forceinline__ float wave_reduce(float v) {
    #pragma unroll
    for (int m = 32; m >= 1; m >>= 1) v += __shfl_xor(v, m, 64);
    return v;
}

__device__ __forceinline__ float dot4(float4 a, float4 b) {
    return a.x*b.x + a.y*b.y + a.z*b.z + a.w*b.w;
}

__device__ __forceinline__ int bucket_of(float t) {
    return min(max((int)(t * 16384.0f), 0), NBUCKET - 1);   // pow2 scale, monotone
}

__device__ __forceinline__ unsigned long long key_of(float t, int i) {
    // stable argsort(-t): j at-or-before i (j!=i)  <=>  key_j > key_i
    return (((unsigned long long)__float_as_uint(t)) << 14) |
           (unsigned long long)(B_N - 1 - i);
}

// ---------------------------------------------------------------------------
// k_prep: 16 blocks x 1024. Histogram expsums + per-bucket linked list + NLL.
// Last block to finish (device-scope counter) scans buckets -> cumH
// (cumH[b] = sum of sumE over buckets strictly greater than b).
// ---------------------------------------------------------------------------
__global__ __launch_bounds__(1024) void k_prep(
        const float* __restrict__ hazard,
        const float* __restrict__ score,
        const float* __restrict__ time,
        const int*   __restrict__ event,
        float* __restrict__ scal,        // [0]=cox [1]=nll [2]=ev [3]=con
        int*   __restrict__ counters,    // [0]=prep done, [1]=main done
        float* __restrict__ sumE,        // [NBUCKET]
        int*   __restrict__ head,        // [NBUCKET], 0 = empty, else j+1
        int*   __restrict__ next,        // [B_N]
        float* __restrict__ cumH)        // [NBUCKET]
{
    __shared__ float lsf[1024];
    __shared__ int last_sh;
    const int tid  = threadIdx.x;
    const int lane = tid & 63;

    const int i = blockIdx.x * 1024 + tid;
    const float t = time[i];
    const float h = hazard[i];
    const int  ev = event[i];
    const float e = __expf(h);
    const int   b = bucket_of(t);

    atomicAdd(&sumE[b], e);
    const int old = atomicExch(&head[b], i + 1);
    next[i] = old;

    float nll_p = score[i * 2 + ev];
    float ev_p  = (float)ev;
    nll_p = wave_reduce(nll_p);
    ev_p  = wave_reduce(ev_p);
    if (lane == 0) { atomicAdd(&scal[1], nll_p); atomicAdd(&scal[2], ev_p); }

    __threadfence();
    __syncthreads();
    if (tid == 0) last_sh = atomicAdd(&counters[0], 1);
    __syncthreads();

    if (last_sh == PREP_BLOCKS - 1) {
        // all other blocks' atomics are globally visible (fence + atomic order)
        volatile float* vs = sumE;       // volatile -> L1-bypassing loads
        const int base = tid * (NBUCKET / 1024);   // 16 buckets per thread
        float f[16]; float fs = 0.f;
        #pragma unroll
        for (int k = 0; k < 16; ++k) { f[k] = vs[base + k]; fs += f[k]; }
        lsf[tid] = fs;
        __syncthreads();
        for (int d = 1; d < 1024; d <<= 1) {
            float v = (tid >= d) ? lsf[tid - d] : 0.f;
            __syncthreads();
            lsf[tid] += v;
            __syncthreads();
        }
        const float total = lsf[1023];
        float run = total - lsf[tid];    // sum of chunks strictly after mine
        #pragma unroll
        for (int k = 15; k >= 0; --k) { cumH[base + k] = run; run += f[k]; }
    }
}

// ---------------------------------------------------------------------------
// k_main: 2048 con blocks (4 waves x 1 pair) + 64 cox blocks (256 elements).
// Last finishing block writes out[0].
// ---------------------------------------------------------------------------
__global__ __launch_bounds__(256) void k_main(
        const float* __restrict__ rep1,
        const float* __restrict__ rep2,
        const float* __restrict__ rep3,
        const float* __restrict__ hazard,
        const float* __restrict__ time,
        const int*   __restrict__ event,
        const int*   __restrict__ x1_idx,
        const int*   __restrict__ x2_idx,
        float* __restrict__ scal,
        int*   __restrict__ counters,
        const int*   __restrict__ head,
        const int*   __restrict__ next,
        const float* __restrict__ cumH,
        float* __restrict__ out)
{
    __shared__ float wsum[4];
    const int tid  = threadIdx.x;
    const int lane = tid & 63;
    const int wave = tid >> 6;

    if (blockIdx.x < CON_BLOCKS) {
        // ---------------- contrastive ----------------
        const int p  = blockIdx.x * 4 + wave;
        const int ia = x1_idx[p];
        const int ib = x2_idx[p];
        const float4* A1 = (const float4*)(rep1 + (size_t)ia * D_N);
        const float4* A2 = (const float4*)(rep2 + (size_t)ia * D_N);
        const float4* A3 = (const float4*)(rep3 + (size_t)ia * D_N);
        const float4* B1 = (const float4*)(rep1 + (size_t)ib * D_N);
        const float4* B2 = (const float4*)(rep2 + (size_t)ib * D_N);
        const float4* B3 = (const float4*)(rep3 + (size_t)ib * D_N);

        float v[15];
        #pragma unroll
        for (int k = 0; k < 15; ++k) v[k] = 0.f;
        #pragma unroll
        for (int r = 0; r < 2; ++r) {
            const int k = lane + r * 64;           // 128 float4 per row
            float4 a1 = A1[k], a2 = A2[k], a3 = A3[k];
            float4 b1 = B1[k], b2 = B2[k], b3 = B3[k];
            v[0]  += dot4(a1, a1); v[1]  += dot4(a2, a2); v[2]  += dot4(a3, a3);
            v[3]  += dot4(b1, b1); v[4]  += dot4(b2, b2); v[5]  += dot4(b3, b3);
            v[6]  += dot4(a1, a2); v[7]  += dot4(a1, a3); v[8]  += dot4(a2, a3);
            v[9]  += dot4(b1, b2); v[10] += dot4(b1, b3); v[11] += dot4(b2, b3);
            v[12] += dot4(a1, b1); v[13] += dot4(a2, b2); v[14] += dot4(a3, b3);
        }
        #pragma unroll
        for (int k = 0; k < 15; ++k) v[k] = wave_reduce(v[k]);

        if (lane == 0) {
            float n1a = fmaxf(sqrtf(v[0]), 1e-8f), n2a = fmaxf(sqrtf(v[1]), 1e-8f), n3a = fmaxf(sqrtf(v[2]), 1e-8f);
            float n1b = fmaxf(sqrtf(v[3]), 1e-8f), n2b = fmaxf(sqrtf(v[4]), 1e-8f), n3b = fmaxf(sqrtf(v[5]), 1e-8f);
            float dxx = v[6]/(n1a*n2a) + v[7]/(n1a*n3a) + v[8]/(n2a*n3a);
            float dyy = v[9]/(n1b*n2b) + v[10]/(n1b*n3b) + v[11]/(n2b*n3b);
            float dxy = v[12]/(n1a*n1b) + v[13]/(n2a*n2b) + v[14]/(n3a*n3b);
            float s = 0.2f + dxy - 0.5f*dxx - 0.5f*dyy;
            wsum[wave] = log1pf(expf(s));
        }
        __syncthreads();
        if (tid == 0)
            atomicAdd(&scal[3], wsum[0] + wsum[1] + wsum[2] + wsum[3]);
    } else {
        // ---------------- cox correction ----------------
        const int i = (blockIdx.x - CON_BLOCKS) * 256 + tid;
        const float t = time[i];
        const float h = hazard[i];
        const int  ev = event[i];
        const float e = __expf(h);
        const int   b = bucket_of(t);
        const unsigned long long ki = key_of(t, i);

        float cum = cumH[b] + e;               // strictly-greater buckets + self
        int p = head[b];
        while (p) {
            const int j = p - 1;
            const float tj = time[j];
            if (key_of(tj, j) > ki) cum += __expf(hazard[j]);
            p = next[j];
        }
        float cox_p = ev ? (h - logf(cum + 1e-6f)) : 0.f;
        cox_p = wave_reduce(cox_p);
        if (lane == 0) atomicAdd(&scal[0], cox_p);
    }

    // ---------------- last-block finalize ----------------
    __threadfence();
    __syncthreads();
    if (tid == 0) {
        const int old = atomicAdd(&counters[1], 1);
        if (old == TOT_BLOCKS - 1) {
            volatile float* vs = scal;
            const float X = vs[0], N = vs[1], E = vs[2], C = vs[3];
            const float nll_t = -N / (float)B_N;
            const float cox_t = -X / (E + 1e-6f);
            const float con_t = C / (float)NPAIR;
            out[0] = nll_t + cox_t + 0.3f * con_t;
        }
    }
}

extern "C" void kernel_launch(void* const* d_in, const int* in_sizes, int n_in,
                              void* d_out, int out_size, void* d_ws, size_t ws_size,
                              hipStream_t stream)
{
    const float* rep1   = (const float*)d_in[0];
    const float* rep2   = (const float*)d_in[1];
    const float* rep3   = (const float*)d_in[2];
    const float* hazard = (const float*)d_in[3];
    const float* score  = (const float*)d_in[4];
    const float* time_  = (const float*)d_in[5];
    const int*   event  = (const int*)d_in[6];
    const int*   x1     = (const int*)d_in[7];
    const int*   x2     = (const int*)d_in[8];
    float* out = (float*)d_out;

    char* w = (char*)d_ws;
    float* scal     = (float*)(w + 0);              // 16 B
    int*   counters = (int*)  (w + 16);             // 8 B (pad to 64)
    float* sumE     = (float*)(w + 64);             // 64 KB
    int*   head     = (int*)  (w + 64 + 65536);     // 64 KB
    // --- zeroed region ends at 64 + 131072 = 131136 bytes ---
    int*   next     = (int*)  (w + 131136);         // 64 KB (fully written in k_prep)
    float* cumH     = (float*)(w + 196672);         // 64 KB (fully written in k_prep)

    hipMemsetAsync(d_ws, 0, 131136, stream);
    k_prep <<<PREP_BLOCKS, 1024, 0, stream>>>(hazard, score, time_, event,
                                              scal, counters, sumE, head, next, cumH);
    k_main <<<TOT_BLOCKS, 256, 0, stream>>>(rep1, rep2, rep3, hazard, time_, event,
                                            x1, x2, scal, counters, head, next, cumH, out);
}

// Round 6
// 156.512 us; speedup vs baseline: 3.1633x; 2.4826x over previous
//
#include <hip/hip_runtime.h>
#include <math.h>

#define B_N     16384
#define D_N     512
#define NPAIR   8192
#define NBUCKET 16384
#define CON_BLOCKS 2048
#define CHAIN_BLOCKS 64

__device__ __forceinline__ float wave_reduce(float v) {
    #pragma unroll
    for (int m = 32; m >= 1; m >>= 1) v += __shfl_xor(v, m, 64);
    return v;
}

__device__ __forceinline__ float dot4(float4 a, float4 b) {
    return a.x*b.x + a.y*b.y + a.z*b.z + a.w*b.w;
}

__device__ __forceinline__ int bucket_of(float t) {
    return min(max((int)(t * 16384.0f), 0), NBUCKET - 1);   // pow2 scale, monotone
}

__device__ __forceinline__ unsigned long long key_of(float t, int i) {
    // stable argsort(-t): j at-or-before i (j!=i)  <=>  key_j > key_i
    return (((unsigned long long)__float_as_uint(t)) << 14) |
           (unsigned long long)(B_N - 1 - i);
}

// ---------------------------------------------------------------------------
// k_stats: 64 x 256. Bucket histogram (random-address atomics, benign) +
// block-reduced NLL / event-count partials (pure stores, no hot atomics).
// ---------------------------------------------------------------------------
__global__ __launch_bounds__(256) void k_stats(
        const float* __restrict__ hazard,
        const float* __restrict__ score,
        const float* __restrict__ time,
        const int*   __restrict__ event,
        int*   __restrict__ counts,
        float* __restrict__ sumE,
        float* __restrict__ partNll,
        float* __restrict__ partEv)
{
    __shared__ float shN[4], shE[4];
    const int tid  = threadIdx.x;
    const int lane = tid & 63;
    const int wave = tid >> 6;
    const int i = blockIdx.x * 256 + tid;

    const float t = time[i];
    const float e = __expf(hazard[i]);
    const int   b = bucket_of(t);
    atomicAdd(&counts[b], 1);
    atomicAdd(&sumE[b], e);

    const int ev = event[i];
    float nll_p = wave_reduce(score[i * 2 + ev]);
    float ev_p  = wave_reduce((float)ev);
    if (lane == 0) { shN[wave] = nll_p; shE[wave] = ev_p; }
    __syncthreads();
    if (tid == 0) {
        partNll[blockIdx.x] = shN[0] + shN[1] + shN[2] + shN[3];
        partEv[blockIdx.x]  = shE[0] + shE[1] + shE[2] + shE[3];
    }
}

// ---------------------------------------------------------------------------
// k_scan: 1 x 1024. pos = exclusive prefix of counts;
// cumH[b] = sum of sumE over buckets strictly greater than b.
// ---------------------------------------------------------------------------
__global__ __launch_bounds__(1024) void k_scan(const int* __restrict__ counts,
                                               const float* __restrict__ sumE,
                                               int* __restrict__ pos,
                                               float* __restrict__ cumH)
{
    __shared__ int   lsi[1024];
    __shared__ float lsf[1024];
    const int tid = threadIdx.x;
    const int base = tid * 16;

    int c[16]; int s = 0;
    #pragma unroll
    for (int k = 0; k < 16; ++k) c[k] = counts[base + k];
    #pragma unroll
    for (int k = 0; k < 16; ++k) { int t = c[k]; c[k] = s; s += t; }
    lsi[tid] = s;
    __syncthreads();
    for (int d = 1; d < 1024; d <<= 1) {
        int v = (tid >= d) ? lsi[tid - d] : 0;
        __syncthreads();
        lsi[tid] += v;
        __syncthreads();
    }
    int ebase = lsi[tid] - s;
    #pragma unroll
    for (int k = 0; k < 16; ++k) pos[base + k] = ebase + c[k];

    float f[16]; float fs = 0.f;
    #pragma unroll
    for (int k = 0; k < 16; ++k) { f[k] = sumE[base + k]; fs += f[k]; }
    lsf[tid] = fs;
    __syncthreads();
    for (int d = 1; d < 1024; d <<= 1) {
        float v = (tid >= d) ? lsf[tid - d] : 0.f;
        __syncthreads();
        lsf[tid] += v;
        __syncthreads();
    }
    const float total = lsf[1023];
    float running = total - lsf[tid];
    #pragma unroll
    for (int k = 15; k >= 0; --k) { cumH[base + k] = running; running += f[k]; }
}

// ---------------------------------------------------------------------------
// k_scatter: 64 x 256. Counting scatter; pos[b] becomes bucket END offset.
// ---------------------------------------------------------------------------
__global__ __launch_bounds__(256) void k_scatter(
        const float* __restrict__ hazard,
        const float* __restrict__ time,
        int* __restrict__ pos,
        unsigned long long* __restrict__ skey,
        float* __restrict__ sev)
{
    const int i = blockIdx.x * 256 + threadIdx.x;
    const float t = time[i];
    const int   b = bucket_of(t);
    const int   p = atomicAdd(&pos[b], 1);
    skey[p] = key_of(t, i);
    sev[p]  = __expf(hazard[i]);
}

// ---------------------------------------------------------------------------
// k_cox: 64 x 256. In-bucket correction over contiguous [pos[b-1], pos[b]).
// Block-reduced partial store.
// ---------------------------------------------------------------------------
__global__ __launch_bounds__(256) void k_cox(
        const float* __restrict__ hazard,
        const float* __restrict__ time,
        const int*   __restrict__ event,
        const int*   __restrict__ pos,
        const float* __restrict__ cumH,
        const unsigned long long* __restrict__ skey,
        const float* __restrict__ sev,
        float* __restrict__ partCox)
{
    __shared__ float shX[4];
    const int tid  = threadIdx.x;
    const int lane = tid & 63;
    const int wave = tid >> 6;
    const int i = blockIdx.x * 256 + tid;

    const float t = time[i];
    const float h = hazard[i];
    const int   b = bucket_of(t);
    const unsigned long long ki = key_of(t, i);

    float cum = cumH[b] + __expf(h);          // strictly-greater buckets + self
    const int lo = (b == 0) ? 0 : pos[b - 1];
    const int hi = pos[b];
    for (int q = lo; q < hi; ++q) {
        if (skey[q] > ki) cum += sev[q];
    }
    float cox_p = event[i] ? (h - logf(cum + 1e-6f)) : 0.f;
    cox_p = wave_reduce(cox_p);
    if (lane == 0) shX[wave] = cox_p;
    __syncthreads();
    if (tid == 0) partCox[blockIdx.x] = shX[0] + shX[1] + shX[2] + shX[3];
}

// ---------------------------------------------------------------------------
// k_con: 2048 x 256 (4 waves, 1 pair each). Pure partial store, no atomics.
// ---------------------------------------------------------------------------
__global__ __launch_bounds__(256) void k_con(const float* __restrict__ rep1,
                                             const float* __restrict__ rep2,
                                             const float* __restrict__ rep3,
                                             const int* __restrict__ x1_idx,
                                             const int* __restrict__ x2_idx,
                                             float* __restrict__ partCon)
{
    __shared__ float wsum[4];
    const int lane = threadIdx.x & 63;
    const int wave = threadIdx.x >> 6;
    const int p = blockIdx.x * 4 + wave;
    const int ia = x1_idx[p];
    const int ib = x2_idx[p];
    const float4* A1 = (const float4*)(rep1 + (size_t)ia * D_N);
    const float4* A2 = (const float4*)(rep2 + (size_t)ia * D_N);
    const float4* A3 = (const float4*)(rep3 + (size_t)ia * D_N);
    const float4* B1 = (const float4*)(rep1 + (size_t)ib * D_N);
    const float4* B2 = (const float4*)(rep2 + (size_t)ib * D_N);
    const float4* B3 = (const float4*)(rep3 + (size_t)ib * D_N);

    float v[15];
    #pragma unroll
    for (int k = 0; k < 15; ++k) v[k] = 0.f;

    #pragma unroll
    for (int r = 0; r < 2; ++r) {
        const int k = lane + r * 64;          // 128 float4 per row
        float4 a1 = A1[k], a2 = A2[k], a3 = A3[k];
        float4 b1 = B1[k], b2 = B2[k], b3 = B3[k];
        v[0]  += dot4(a1, a1); v[1]  += dot4(a2, a2); v[2]  += dot4(a3, a3);
        v[3]  += dot4(b1, b1); v[4]  += dot4(b2, b2); v[5]  += dot4(b3, b3);
        v[6]  += dot4(a1, a2); v[7]  += dot4(a1, a3); v[8]  += dot4(a2, a3);
        v[9]  += dot4(b1, b2); v[10] += dot4(b1, b3); v[11] += dot4(b2, b3);
        v[12] += dot4(a1, b1); v[13] += dot4(a2, b2); v[14] += dot4(a3, b3);
    }
    #pragma unroll
    for (int k = 0; k < 15; ++k) v[k] = wave_reduce(v[k]);

    if (lane == 0) {
        float n1a = fmaxf(sqrtf(v[0]), 1e-8f), n2a = fmaxf(sqrtf(v[1]), 1e-8f), n3a = fmaxf(sqrtf(v[2]), 1e-8f);
        float n1b = fmaxf(sqrtf(v[3]), 1e-8f), n2b = fmaxf(sqrtf(v[4]), 1e-8f), n3b = fmaxf(sqrtf(v[5]), 1e-8f);
        float dxx = v[6]/(n1a*n2a) + v[7]/(n1a*n3a) + v[8]/(n2a*n3a);
        float dyy = v[9]/(n1b*n2b) + v[10]/(n1b*n3b) + v[11]/(n2b*n3b);
        float dxy = v[12]/(n1a*n1b) + v[13]/(n2a*n2b) + v[14]/(n3a*n3b);
        float s = 0.2f + dxy - 0.5f*dxx - 0.5f*dyy;
        wsum[wave] = log1pf(expf(s));
    }
    __syncthreads();
    if (threadIdx.x == 0)
        partCon[blockIdx.x] = wsum[0] + wsum[1] + wsum[2] + wsum[3];
}

// ---------------------------------------------------------------------------
// k_final: 1 x 256. Reduce all partials -> out[0].
// ---------------------------------------------------------------------------
__global__ __launch_bounds__(256) void k_final(const float* __restrict__ partCon,
                                               const float* __restrict__ partCox,
                                               const float* __restrict__ partNll,
                                               const float* __restrict__ partEv,
                                               float* __restrict__ out)
{
    __shared__ float sh[4][4];
    const int tid  = threadIdx.x;
    const int lane = tid & 63;
    const int wave = tid >> 6;

    float con = 0.f;
    #pragma unroll
    for (int k = 0; k < CON_BLOCKS / 256; ++k) con += partCon[tid + k * 256];
    float cox = (tid < CHAIN_BLOCKS) ? partCox[tid] : 0.f;
    float nll = (tid < CHAIN_BLOCKS) ? partNll[tid] : 0.f;
    float ev  = (tid < CHAIN_BLOCKS) ? partEv[tid]  : 0.f;

    con = wave_reduce(con);
    cox = wave_reduce(cox);
    nll = wave_reduce(nll);
    ev  = wave_reduce(ev);
    if (lane == 0) { sh[wave][0] = con; sh[wave][1] = cox; sh[wave][2] = nll; sh[wave][3] = ev; }
    __syncthreads();
    if (tid == 0) {
        float C = sh[0][0] + sh[1][0] + sh[2][0] + sh[3][0];
        float X = sh[0][1] + sh[1][1] + sh[2][1] + sh[3][1];
        float N = sh[0][2] + sh[1][2] + sh[2][2] + sh[3][2];
        float E = sh[0][3] + sh[1][3] + sh[2][3] + sh[3][3];
        out[0] = (-N / (float)B_N) + (-X / (E + 1e-6f)) + 0.3f * (C / (float)NPAIR);
    }
}

extern "C" void kernel_launch(void* const* d_in, const int* in_sizes, int n_in,
                              void* d_out, int out_size, void* d_ws, size_t ws_size,
                              hipStream_t stream)
{
    const float* rep1   = (const float*)d_in[0];
    const float* rep2   = (const float*)d_in[1];
    const float* rep3   = (const float*)d_in[2];
    const float* hazard = (const float*)d_in[3];
    const float* score  = (const float*)d_in[4];
    const float* time_  = (const float*)d_in[5];
    const int*   event  = (const int*)d_in[6];
    const int*   x1     = (const int*)d_in[7];
    const int*   x2     = (const int*)d_in[8];
    float* out = (float*)d_out;

    char* w = (char*)d_ws;
    int*   counts  = (int*)  (w + 0);         // 64 KB  | zeroed
    float* sumE    = (float*)(w + 65536);     // 64 KB  | zeroed
    int*   pos     = (int*)  (w + 131072);    // 64 KB  (written by k_scan)
    float* cumH    = (float*)(w + 196608);    // 64 KB  (written by k_scan)
    unsigned long long* skey = (unsigned long long*)(w + 262144);  // 128 KB (k_scatter)
    float* sev     = (float*)(w + 393216);    // 64 KB  (k_scatter)
    float* partCon = (float*)(w + 458752);    // 8 KB   (k_con)
    float* partCox = (float*)(w + 466944);    // 256 B  (k_cox)
    float* partNll = (float*)(w + 467200);    // 256 B  (k_stats)
    float* partEv  = (float*)(w + 467456);    // 256 B  (k_stats)

    hipMemsetAsync(d_ws, 0, 131072, stream);  // counts + sumE only

    k_stats  <<<CHAIN_BLOCKS, 256, 0, stream>>>(hazard, score, time_, event,
                                                counts, sumE, partNll, partEv);
    k_scan   <<<1, 1024, 0, stream>>>(counts, sumE, pos, cumH);
    k_scatter<<<CHAIN_BLOCKS, 256, 0, stream>>>(hazard, time_, pos, skey, sev);
    k_cox    <<<CHAIN_BLOCKS, 256, 0, stream>>>(hazard, time_, event, pos, cumH,
                                                skey, sev, partCox);
    k_con    <<<CON_BLOCKS, 256, 0, stream>>>(rep1, rep2, rep3, x1, x2, partCon);
    k_final  <<<1, 256, 0, stream>>>(partCon, partCox, partNll, partEv, out);
}

// Round 7
// 150.780 us; speedup vs baseline: 3.2835x; 1.0380x over previous
//
#include <hip/hip_runtime.h>
#include <math.h>

#define B_N     16384
#define D_N     512
#define NPAIR   8192
#define NBUCKET 16384            // avg 1 element/bucket
#define CON_BLOCKS 2048
#define STAT_BLOCKS 64
#define BIG_BLOCKS (CON_BLOCKS + STAT_BLOCKS)
#define COX_BLOCKS 64

__device__ __forceinline__ float wave_reduce(float v) {
    #pragma unroll
    for (int m = 32; m >= 1; m >>= 1) v += __shfl_xor(v, m, 64);
    return v;
}

__device__ __forceinline__ float dot4(float4 a, float4 b) {
    return a.x*b.x + a.y*b.y + a.z*b.z + a.w*b.w;
}

__device__ __forceinline__ int bucket_of(float t) {
    return min(max((int)(t * 16384.0f), 0), NBUCKET - 1);   // pow2 scale, monotone
}

__device__ __forceinline__ unsigned long long key_of(float t, int i) {
    // stable argsort(-t): j at-or-before i (j!=i)  <=>  key_j > key_i
    return (((unsigned long long)__float_as_uint(t)) << 14) |
           (unsigned long long)(B_N - 1 - i);
}

// ---------------------------------------------------------------------------
// k_big: 2112 blocks x 256.
//   blocks 0..2047    : contrastive pairs (4 waves x 1 pair), partial stores
//   blocks 2048..2111 : cox histogram (sumE) + per-bucket linked list + NLL
// The stats work hides entirely under the con blocks' ~20 us memory time.
// ---------------------------------------------------------------------------
__global__ __launch_bounds__(256) void k_big(
        const float* __restrict__ rep1,
        const float* __restrict__ rep2,
        const float* __restrict__ rep3,
        const float* __restrict__ hazard,
        const float* __restrict__ score,
        const float* __restrict__ time,
        const int*   __restrict__ event,
        const int*   __restrict__ x1_idx,
        const int*   __restrict__ x2_idx,
        float* __restrict__ partCon,     // [2048]
        float* __restrict__ partNll,     // [64]
        float* __restrict__ partEv,      // [64]
        float* __restrict__ sumE,        // [NBUCKET] zeroed
        int*   __restrict__ head,        // [NBUCKET] zeroed; 0=empty else j+1
        int*   __restrict__ next)        // [B_N]
{
    __shared__ float sh0[4], sh1[4];
    const int tid  = threadIdx.x;
    const int lane = tid & 63;
    const int wave = tid >> 6;

    if (blockIdx.x < CON_BLOCKS) {
        // ---------------- contrastive ----------------
        const int p  = blockIdx.x * 4 + wave;
        const int ia = x1_idx[p];
        const int ib = x2_idx[p];
        const float4* A1 = (const float4*)(rep1 + (size_t)ia * D_N);
        const float4* A2 = (const float4*)(rep2 + (size_t)ia * D_N);
        const float4* A3 = (const float4*)(rep3 + (size_t)ia * D_N);
        const float4* B1 = (const float4*)(rep1 + (size_t)ib * D_N);
        const float4* B2 = (const float4*)(rep2 + (size_t)ib * D_N);
        const float4* B3 = (const float4*)(rep3 + (size_t)ib * D_N);

        float v[15];
        #pragma unroll
        for (int k = 0; k < 15; ++k) v[k] = 0.f;
        #pragma unroll
        for (int r = 0; r < 2; ++r) {
            const int k = lane + r * 64;           // 128 float4 per row
            float4 a1 = A1[k], a2 = A2[k], a3 = A3[k];
            float4 b1 = B1[k], b2 = B2[k], b3 = B3[k];
            v[0]  += dot4(a1, a1); v[1]  += dot4(a2, a2); v[2]  += dot4(a3, a3);
            v[3]  += dot4(b1, b1); v[4]  += dot4(b2, b2); v[5]  += dot4(b3, b3);
            v[6]  += dot4(a1, a2); v[7]  += dot4(a1, a3); v[8]  += dot4(a2, a3);
            v[9]  += dot4(b1, b2); v[10] += dot4(b1, b3); v[11] += dot4(b2, b3);
            v[12] += dot4(a1, b1); v[13] += dot4(a2, b2); v[14] += dot4(a3, b3);
        }
        #pragma unroll
        for (int k = 0; k < 15; ++k) v[k] = wave_reduce(v[k]);

        if (lane == 0) {
            float n1a = fmaxf(sqrtf(v[0]), 1e-8f), n2a = fmaxf(sqrtf(v[1]), 1e-8f), n3a = fmaxf(sqrtf(v[2]), 1e-8f);
            float n1b = fmaxf(sqrtf(v[3]), 1e-8f), n2b = fmaxf(sqrtf(v[4]), 1e-8f), n3b = fmaxf(sqrtf(v[5]), 1e-8f);
            float dxx = v[6]/(n1a*n2a) + v[7]/(n1a*n3a) + v[8]/(n2a*n3a);
            float dyy = v[9]/(n1b*n2b) + v[10]/(n1b*n3b) + v[11]/(n2b*n3b);
            float dxy = v[12]/(n1a*n1b) + v[13]/(n2a*n2b) + v[14]/(n3a*n3b);
            float s = 0.2f + dxy - 0.5f*dxx - 0.5f*dyy;
            sh0[wave] = log1pf(expf(s));
        }
        __syncthreads();
        if (tid == 0)
            partCon[blockIdx.x] = sh0[0] + sh0[1] + sh0[2] + sh0[3];
    } else {
        // ---------------- cox stats + lists + NLL ----------------
        const int sb = blockIdx.x - CON_BLOCKS;
        const int i  = sb * 256 + tid;
        const float t = time[i];
        const float e = __expf(hazard[i]);
        const int   b = bucket_of(t);
        atomicAdd(&sumE[b], e);                  // device-scope
        const int old = atomicExch(&head[b], i + 1);
        next[i] = old;

        const int ev = event[i];
        float nll_p = wave_reduce(score[i * 2 + ev]);
        float ev_p  = wave_reduce((float)ev);
        if (lane == 0) { sh0[wave] = nll_p; sh1[wave] = ev_p; }
        __syncthreads();
        if (tid == 0) {
            partNll[sb] = sh0[0] + sh0[1] + sh0[2] + sh0[3];
            partEv[sb]  = sh1[0] + sh1[1] + sh1[2] + sh1[3];
        }
    }
}

// ---------------------------------------------------------------------------
// k_scan: 1 x 1024. cumH[b] = sum of sumE over buckets strictly greater than b.
// (kernel boundary guarantees visibility of k_big's atomics)
// ---------------------------------------------------------------------------
__global__ __launch_bounds__(1024) void k_scan(const float* __restrict__ sumE,
                                               float* __restrict__ cumH)
{
    __shared__ float lsf[1024];
    const int tid = threadIdx.x;
    const int base = tid * 16;

    float f[16]; float fs = 0.f;
    #pragma unroll
    for (int k = 0; k < 16; ++k) { f[k] = sumE[base + k]; fs += f[k]; }
    lsf[tid] = fs;
    __syncthreads();
    for (int d = 1; d < 1024; d <<= 1) {
        float v = (tid >= d) ? lsf[tid - d] : 0.f;
        __syncthreads();
        lsf[tid] += v;
        __syncthreads();
    }
    const float total = lsf[1023];
    float running = total - lsf[tid];            // buckets after my chunk
    #pragma unroll
    for (int k = 15; k >= 0; --k) { cumH[base + k] = running; running += f[k]; }
}

// ---------------------------------------------------------------------------
// k_cox: 64 x 256. List-walk in-bucket correction (avg 1 hop) + fused final.
// Last-finishing block (64-block done counter) combines all partials -> out.
// ---------------------------------------------------------------------------
__global__ __launch_bounds__(256) void k_cox(
        const float* __restrict__ hazard,
        const float* __restrict__ time,
        const int*   __restrict__ event,
        const int*   __restrict__ head,
        const int*   __restrict__ next,
        const float* __restrict__ cumH,
        const float* __restrict__ partCon,
        const float* __restrict__ partNll,
        const float* __restrict__ partEv,
        float* __restrict__ partCox,     // [64]
        int*   __restrict__ doneCox,     // zeroed
        float* __restrict__ out)
{
    __shared__ float shX[4];
    __shared__ int lastflag;
    const int tid  = threadIdx.x;
    const int lane = tid & 63;
    const int wave = tid >> 6;
    const int i = blockIdx.x * 256 + tid;

    const float t = time[i];
    const float h = hazard[i];
    const int   b = bucket_of(t);
    const unsigned long long ki = key_of(t, i);

    float cum = cumH[b] + __expf(h);             // strictly-greater buckets + self
    int p = head[b];
    while (p) {
        const int j = p - 1;
        const float tj = time[j];
        if (key_of(tj, j) > ki) cum += __expf(hazard[j]);   // j==i: keys equal, skipped
        p = next[j];
    }
    float cox_p = event[i] ? (h - logf(cum + 1e-6f)) : 0.f;
    cox_p = wave_reduce(cox_p);
    if (lane == 0) shX[wave] = cox_p;
    __syncthreads();
    if (tid == 0)
        atomicExch(&partCox[blockIdx.x], shX[0] + shX[1] + shX[2] + shX[3]);

    // ---- last-block finalize (64-block counter; coherent atomic pub/read) ----
    __threadfence();
    if (tid == 0) lastflag = (atomicAdd(doneCox, 1) == COX_BLOCKS - 1);
    __syncthreads();
    if (lastflag) {
        float con = 0.f;
        #pragma unroll
        for (int k = 0; k < CON_BLOCKS / 256; ++k) con += partCon[tid + k * 256];
        float cox = 0.f, nll = 0.f, ev = 0.f;
        if (tid < COX_BLOCKS) {
            cox = atomicAdd(&partCox[tid], 0.f); // coherent read of sibling stores
            nll = partNll[tid];                  // prior kernel -> plain load ok
            ev  = partEv[tid];
        }
        con = wave_reduce(con);
        cox = wave_reduce(cox);
        nll = wave_reduce(nll);
        ev  = wave_reduce(ev);
        __syncthreads();                          // reuse shX safely
        if (lane == 0) { shX[wave] = con; }
        __syncthreads();
        float C = shX[0] + shX[1] + shX[2] + shX[3];
        if (lane == 0) { shX[wave] = cox; }
        __syncthreads();
        float X = shX[0] + shX[1] + shX[2] + shX[3];
        if (lane == 0) { shX[wave] = nll; }
        __syncthreads();
        float N = shX[0] + shX[1] + shX[2] + shX[3];
        if (lane == 0) { shX[wave] = ev; }
        __syncthreads();
        float E = shX[0] + shX[1] + shX[2] + shX[3];
        if (tid == 0)
            out[0] = (-N / (float)B_N) + (-X / (E + 1e-6f)) + 0.3f * (C / (float)NPAIR);
    }
}

extern "C" void kernel_launch(void* const* d_in, const int* in_sizes, int n_in,
                              void* d_out, int out_size, void* d_ws, size_t ws_size,
                              hipStream_t stream)
{
    const float* rep1   = (const float*)d_in[0];
    const float* rep2   = (const float*)d_in[1];
    const float* rep3   = (const float*)d_in[2];
    const float* hazard = (const float*)d_in[3];
    const float* score  = (const float*)d_in[4];
    const float* time_  = (const float*)d_in[5];
    const int*   event  = (const int*)d_in[6];
    const int*   x1     = (const int*)d_in[7];
    const int*   x2     = (const int*)d_in[8];
    float* out = (float*)d_out;

    char* w = (char*)d_ws;
    float* sumE    = (float*)(w + 0);             // 64 KB | zeroed
    int*   head    = (int*)  (w + 65536);         // 64 KB | zeroed
    int*   doneCox = (int*)  (w + 131072);        // 64 B  | zeroed
    // ---- zeroed region: [0, 131136) ----
    int*   next    = (int*)  (w + 131136);        // 64 KB (k_big)
    float* cumH    = (float*)(w + 196672);        // 64 KB (k_scan)
    float* partCon = (float*)(w + 262208);        // 8 KB  (k_big)
    float* partNll = (float*)(w + 270400);        // 256 B (k_big)
    float* partEv  = (float*)(w + 270656);        // 256 B (k_big)
    float* partCox = (float*)(w + 270912);        // 256 B (k_cox)

    hipMemsetAsync(d_ws, 0, 131136, stream);

    k_big  <<<BIG_BLOCKS, 256, 0, stream>>>(rep1, rep2, rep3, hazard, score, time_,
                                            event, x1, x2, partCon, partNll, partEv,
                                            sumE, head, next);
    k_scan <<<1, 1024, 0, stream>>>(sumE, cumH);
    k_cox  <<<COX_BLOCKS, 256, 0, stream>>>(hazard, time_, event, head, next, cumH,
                                            partCon, partNll, partEv, partCox,
                                            doneCox, out);
}